// Round 9
// baseline (889.687 us; speedup 1.0000x reference)
//
#include <hip/hip_runtime.h>
#include <math.h>

// ---------------------------------------------------------------------------
// 2-layer GraphSAGE (mean aggr) + link predictor. bf16 MFMA, folded layer 2,
// bucketed edge records (no CSR fill, no esrc, no h buffer).
//
//   prep: cast x->bf16 | W1->W1t bf16 | fold W2/Wlin/b2 | bucket hist
//   bucket_scan (1 block) -> scatter (64 blocks, dense 4B records)
//   agg1_bucket: LDS fp32 accumulate x rows per 64-node bucket -> meanh,invdeg
//   gemm1+gemv: h=relu([meanh|xh]@W1+b1) in-reg, dot with folded vecs -> pab,quv
//   agg_link: LDS accumulate pab scalars per bucket -> za, zb
//   link: sigmoid(za[ps]+zb[pd]+blin)
// ---------------------------------------------------------------------------

typedef __attribute__((ext_vector_type(8))) short bf16x8;
typedef __attribute__((ext_vector_type(4))) float f32x4;
typedef unsigned int uint32;
typedef unsigned short ushort16;

#define MAXBUCK 784   // buckets of 64 nodes; N<=50176

__device__ __forceinline__ ushort16 f2bf(float f) {
    uint32 u = __float_as_uint(f);
    uint32 r = u + 0x7FFFu + ((u >> 16) & 1u);   // round-to-nearest-even
    return (ushort16)(r >> 16);
}

// ---- fused prep: cast_x | cast_w1 | fold_w2 | bucket hist ------------------

__global__ __launch_bounds__(256)
void prep_kernel(const float* __restrict__ x, uint32* __restrict__ xh, long long n4,
                 const float* __restrict__ W1l, const float* __restrict__ W1r,
                 ushort16* __restrict__ W1t,
                 const float* __restrict__ W2l, const float* __restrict__ W2r,
                 const float* __restrict__ Wlin, const float* __restrict__ b2,
                 float* __restrict__ fw, float* __restrict__ fc,
                 const int* __restrict__ dst, int* __restrict__ bcount, int E,
                 int nbx, int nbw1, int nhb) {
    __shared__ int lh[MAXBUCK];
    int b = blockIdx.x;
    int t = threadIdx.x;
    if (b < nbx) {
        long long i = (long long)b * 256 + t;
        if (i < n4) {
            float4 v = ((const float4*)x)[i];
            uint2 o;
            o.x = (uint32)f2bf(v.x) | ((uint32)f2bf(v.y) << 16);
            o.y = (uint32)f2bf(v.z) | ((uint32)f2bf(v.w) << 16);
            ((uint2*)xh)[i] = o;
        }
    } else if (b < nbx + nbw1) {
        int idx = (b - nbx) * 256 + t;            // 32768: W1t[n][k], k<128->W1l
        int n = idx >> 8, k = idx & 255;
        float v = (k < 128) ? W1l[k * 128 + n] : W1r[(k - 128) * 128 + n];
        W1t[n * 256 + k] = f2bf(v);
    } else if (b == nbx + nbw1) {
        // fold layer-2 weights with link weights: fw = [va|vc|vbp|vd]
        if (t < 128) {
            float a = 0.f, c = 0.f;
            for (int l = 0; l < 64; ++l) {
                float w = W2l[t * 64 + l];
                a += w * Wlin[l];
                c += w * Wlin[64 + l];
            }
            fw[t] = a; fw[128 + t] = c;
        } else {
            int k = t - 128;
            float a = 0.f, c = 0.f;
            for (int l = 0; l < 64; ++l) {
                float w = W2r[k * 64 + l];
                a += w * Wlin[l];
                c += w * Wlin[64 + l];
            }
            fw[256 + k] = a; fw[384 + k] = c;
        }
        if (t == 0) { float s = 0.f; for (int l = 0; l < 64; ++l) s += b2[l] * Wlin[l];      fc[0] = s; }
        if (t == 1) { float s = 0.f; for (int l = 0; l < 64; ++l) s += b2[l] * Wlin[64 + l]; fc[1] = s; }
    } else {
        int hb = b - nbx - nbw1 - 1;              // 0..nhb-1
        for (int i = t; i < MAXBUCK; i += 256) lh[i] = 0;
        __syncthreads();
        int per = (E + nhb - 1) / nhb;
        int e0 = hb * per, e1 = min(e0 + per, E);
        for (int e = e0 + t; e < e1; e += 256) atomicAdd(&lh[dst[e] >> 6], 1);
        __syncthreads();
        for (int i = t; i < MAXBUCK; i += 256)
            if (lh[i]) atomicAdd(&bcount[i], lh[i]);
    }
}

// ---- bucket scan (1 block, 256 threads, 4 elems/thread) --------------------

__global__ void bucket_scan_kernel(const int* __restrict__ bcount,
                                   int* __restrict__ bbase,
                                   int* __restrict__ bcursor, int nbuck) {
    __shared__ int part[256];
    int t = threadIdx.x;
    int lo = t * 4;
    int hi = min(lo + 4, nbuck);
    int loc[4];
    int s = 0;
    for (int i = lo; i < hi; ++i) { loc[i - lo] = bcount[i]; s += loc[i - lo]; }
    part[t] = s;
    __syncthreads();
    for (int off = 1; off < 256; off <<= 1) {
        int v = (t >= off) ? part[t - off] : 0;
        __syncthreads();
        part[t] += v;
        __syncthreads();
    }
    int run = (t == 0) ? 0 : part[t - 1];
    for (int i = lo; i < hi; ++i) {
        bbase[i] = run; bcursor[i] = run; run += loc[i - lo];
    }
    if (t == 255) bbase[nbuck] = part[255];
}

// ---- scatter edges into bucket-ordered 4B records --------------------------
// record = src | (dst&63)<<16 ; per-(block,bucket) runs are dense (~64B lines)

__global__ __launch_bounds__(256)
void scatter_kernel(const int* __restrict__ src, const int* __restrict__ dst,
                    int* __restrict__ bcursor, uint32* __restrict__ recs,
                    int E, int nsb) {
    __shared__ int lh[MAXBUCK];
    __shared__ int lb[MAXBUCK];
    int t = threadIdx.x;
    int per = (E + nsb - 1) / nsb;
    int e0 = blockIdx.x * per, e1 = min(e0 + per, E);
    for (int i = t; i < MAXBUCK; i += 256) lh[i] = 0;
    __syncthreads();
    for (int e = e0 + t; e < e1; e += 256) atomicAdd(&lh[dst[e] >> 6], 1);
    __syncthreads();
    for (int i = t; i < MAXBUCK; i += 256) {
        int c = lh[i];
        lb[i] = c ? atomicAdd(&bcursor[i], c) : 0;
    }
    __syncthreads();
    for (int i = t; i < MAXBUCK; i += 256) lh[i] = 0;
    __syncthreads();
    for (int e = e0 + t; e < e1; e += 256) {
        int d = dst[e];
        int b = d >> 6;
        int r = atomicAdd(&lh[b], 1);
        recs[lb[b] + r] = (uint32)src[e] | ((uint32)(d & 63) << 16);
    }
}

// ---- layer-1 aggregation: LDS fp32 accumulator per 64-node bucket ----------
// lane l accumulates features (2l, 2l+1) stored at lacc[dl*128 + l] / [+64+l]
// (banks spread: 2-way aliasing only, free per m136)

__global__ __launch_bounds__(256, 4)
void agg1_bucket_kernel(const uint32* __restrict__ xh,
                        const uint32* __restrict__ recs,
                        const int* __restrict__ bbase,
                        uint32* __restrict__ meanh,
                        float* __restrict__ invdeg, int N) {
    __shared__ float lacc[64 * 128];
    __shared__ int lcnt[64];
    int t = threadIdx.x;
    for (int i = t; i < 8192; i += 256) lacc[i] = 0.f;
    if (t < 64) lcnt[t] = 0;
    __syncthreads();
    int b = blockIdx.x;
    int s0 = bbase[b], s1 = bbase[b + 1];
    int w = t >> 6, lane = t & 63;
    int cnt = s1 - s0;
    int chunk = (cnt + 3) >> 2;
    int ws = s0 + w * chunk;
    int we = min(ws + chunk, s1);
    for (int i = ws; i < we; i += 8) {
        uint32 rc[8];
        #pragma unroll
        for (int j = 0; j < 8; ++j) rc[j] = recs[(i + j < we) ? i + j : i];
        uint32 xv[8];
        #pragma unroll
        for (int j = 0; j < 8; ++j)
            xv[j] = xh[(size_t)(rc[j] & 0xFFFFu) * 64 + lane];
        #pragma unroll
        for (int j = 0; j < 8; ++j) {
            if (i + j < we) {
                int dl = rc[j] >> 16;
                atomicAdd(&lacc[dl * 128 + lane],      __uint_as_float(xv[j] << 16));
                atomicAdd(&lacc[dl * 128 + 64 + lane], __uint_as_float(xv[j] & 0xFFFF0000u));
                if (lane == 0) atomicAdd(&lcnt[dl], 1);
            }
        }
    }
    __syncthreads();
    int node0 = b * 64;
    #pragma unroll 4
    for (int g = 0; g < 16; ++g) {
        int n = g * 4 + w;
        int gn = node0 + n;
        if (gn < N) {
            float inv = 1.0f / fmaxf((float)lcnt[n], 1.0f);
            float sx = lacc[n * 128 + lane] * inv;
            float sy = lacc[n * 128 + 64 + lane] * inv;
            meanh[(size_t)gn * 64 + lane] = (uint32)f2bf(sx) | ((uint32)f2bf(sy) << 16);
        }
    }
    if (t < 64 && node0 + t < N)
        invdeg[node0 + t] = 1.0f / fmaxf((float)lcnt[t], 1.0f);
}

// ---- MFMA GEMM1 + fused GEMV epilogue --------------------------------------
// Per-wave 16 rows x 128 cols, 8 MFMA 16x16x32. h kept in registers only:
// relu(acc+b1), then dot with folded vectors va/vc/vbp/vd -> pab, quv.
// A-frag: A[m=lane&15][k=quad*8+j]; D: row=quad*4+r, col=lane&15 (m89/m91).

__global__ __launch_bounds__(256)
void gemm1_mfma_kernel(const ushort16* __restrict__ meanh,
                       const ushort16* __restrict__ xh,
                       const ushort16* __restrict__ W1t,
                       const float* __restrict__ b1,
                       const float* __restrict__ fw,
                       float2* __restrict__ pab, float2* __restrict__ quv, int N) {
    int wave = threadIdx.x >> 6;
    int lane = threadIdx.x & 63;
    int m = lane & 15;
    int quad = lane >> 4;
    int row0 = blockIdx.x * 64 + wave * 16;
    int arow = row0 + m; if (arow > N - 1) arow = N - 1;
    f32x4 acc[8];
    #pragma unroll
    for (int c = 0; c < 8; ++c) acc[c] = (f32x4){0.f, 0.f, 0.f, 0.f};
    #pragma unroll
    for (int ks = 0; ks < 8; ++ks) {
        int k0 = ks * 32;
        const ushort16* Ab = (ks < 4) ? meanh : xh;
        bf16x8 a = *(const bf16x8*)(Ab + (size_t)arow * 128 + (k0 & 127) + quad * 8);
        #pragma unroll
        for (int c = 0; c < 8; ++c) {
            bf16x8 b = *(const bf16x8*)(W1t + (size_t)(c * 16 + m) * 256 + k0 + quad * 8);
            acc[c] = __builtin_amdgcn_mfma_f32_16x16x32_bf16(a, b, acc[c], 0, 0, 0);
        }
    }
    float da[4] = {}, dc[4] = {}, db[4] = {}, dd[4] = {};
    #pragma unroll
    for (int c = 0; c < 8; ++c) {
        int col = c * 16 + m;
        float bias = b1[col];
        float wa = fw[col], wc = fw[128 + col], wb = fw[256 + col], wd = fw[384 + col];
        #pragma unroll
        for (int r = 0; r < 4; ++r) {
            float v = fmaxf(acc[c][r] + bias, 0.f);
            da[r] += v * wa; dc[r] += v * wc; db[r] += v * wb; dd[r] += v * wd;
        }
    }
    #pragma unroll
    for (int r = 0; r < 4; ++r) {
        #pragma unroll
        for (int msk = 1; msk < 16; msk <<= 1) {
            da[r] += __shfl_xor(da[r], msk, 64);
            dc[r] += __shfl_xor(dc[r], msk, 64);
            db[r] += __shfl_xor(db[r], msk, 64);
            dd[r] += __shfl_xor(dd[r], msk, 64);
        }
    }
    if (m == 0) {
        #pragma unroll
        for (int r = 0; r < 4; ++r) {
            int grow = row0 + quad * 4 + r;
            if (grow < N) {
                pab[grow] = make_float2(da[r], dc[r]);
                quv[grow] = make_float2(db[r], dd[r]);
            }
        }
    }
}

// ---- layer-2 aggregation on folded scalars (bucket-local LDS) --------------

__global__ __launch_bounds__(256)
void agg_link_kernel(const float2* __restrict__ pab, const float2* __restrict__ quv,
                     const uint32* __restrict__ recs, const int* __restrict__ bbase,
                     const float* __restrict__ invdeg, const float* __restrict__ fc,
                     float* __restrict__ za, float* __restrict__ zb, int N) {
    __shared__ float lacc[128];
    int t = threadIdx.x;
    if (t < 128) lacc[t] = 0.f;
    __syncthreads();
    int b = blockIdx.x;
    int s0 = bbase[b], s1 = bbase[b + 1];
    for (int i = s0 + t; i < s1; i += 1024) {
        uint32 rc[4]; float2 pv[4]; int ok[4];
        #pragma unroll
        for (int j = 0; j < 4; ++j) {
            int k = i + j * 256;
            ok[j] = (k < s1);
            rc[j] = recs[ok[j] ? k : i];
        }
        #pragma unroll
        for (int j = 0; j < 4; ++j) pv[j] = pab[rc[j] & 0xFFFFu];
        #pragma unroll
        for (int j = 0; j < 4; ++j) {
            if (ok[j]) {
                int dl = rc[j] >> 16;
                atomicAdd(&lacc[dl], pv[j].x);
                atomicAdd(&lacc[64 + dl], pv[j].y);
            }
        }
    }
    __syncthreads();
    if (t < 64) {
        int n = b * 64 + t;
        if (n < N) {
            float inv = invdeg[n];
            float2 q = quv[n];
            za[n] = lacc[t] * inv + q.x + fc[0];
            zb[n] = lacc[64 + t] * inv + q.y + fc[1];
        }
    }
}

// ---- link prediction: out[p] = sigmoid(za[ps] + zb[pd] + blin) -------------

__global__ void link_kernel(const float* __restrict__ za, const float* __restrict__ zb,
                            const int* __restrict__ ps, const int* __restrict__ pd,
                            const float* __restrict__ blin,
                            float* __restrict__ out, int P) {
    int p = blockIdx.x * blockDim.x + threadIdx.x;
    if (p >= P) return;
    float logit = za[ps[p]] + zb[pd[p]] + blin[0];
    out[p] = 1.0f / (1.0f + expf(-logit));
}

// ---------------------------------------------------------------------------

extern "C" void kernel_launch(void* const* d_in, const int* in_sizes, int n_in,
                              void* d_out, int out_size, void* d_ws, size_t ws_size,
                              hipStream_t stream) {
    const float* x          = (const float*)d_in[0];
    const int*   edge_index = (const int*)d_in[1];
    const int*   edge_pairs = (const int*)d_in[2];
    const float* W1l        = (const float*)d_in[3];
    const float* b1         = (const float*)d_in[4];
    const float* W1r        = (const float*)d_in[5];
    const float* W2l        = (const float*)d_in[6];
    const float* b2         = (const float*)d_in[7];
    const float* W2r        = (const float*)d_in[8];
    const float* Wlin       = (const float*)d_in[9];
    const float* blin       = (const float*)d_in[10];
    float* out = (float*)d_out;

    const int N = in_sizes[0] / 128;       // 50000
    const int E = in_sizes[1] / 2;         // 800000
    const int P = in_sizes[2] / 2;         // 200000
    const int NBUCK = (N + 63) >> 6;       // 782

    const int* src = edge_index;
    const int* dst = edge_index + E;
    const int* ps  = edge_pairs;
    const int* pd  = edge_pairs + P;

    // workspace layout
    ushort16* xh    = (ushort16*)d_ws;                 // N*128 bf16
    ushort16* meanh = xh + (size_t)N * 128;            // N*128 bf16
    ushort16* W1t   = meanh + (size_t)N * 128;         // 128*256 bf16
    float* fw      = (float*)(W1t + 128 * 256);        // 512 f32
    float* fc      = fw + 512;                         // 2 f32 (+2 pad)
    float2* pab    = (float2*)(fc + 4);                // N float2
    float2* quv    = pab + N;                          // N float2
    float* za      = (float*)(quv + N);                // N f32
    float* zb      = za + N;                           // N f32
    float* invdeg  = zb + N;                           // N f32
    int* bcount    = (int*)(invdeg + N);               // NBUCK+1
    int* bbase     = bcount + (MAXBUCK + 16);          // NBUCK+1
    int* bcursor   = bbase + (MAXBUCK + 16);           // NBUCK
    uint32* recs   = (uint32*)(bcursor + (MAXBUCK + 16)); // E records

    const long long n4 = (long long)N * 128 / 4;       // 1.6M
    const int nbx  = (int)((n4 + 255) / 256);          // 6250
    const int nbw1 = 128;
    const int nhb  = 64;                               // bucket-hist blocks
    const int nsb  = 64;                               // scatter blocks

    hipMemsetAsync(bcount, 0, (size_t)(MAXBUCK + 16) * sizeof(int), stream);

    // fused prep: cast x, cast+transpose W1, fold W2/Wlin/b2, bucket histogram
    prep_kernel<<<nbx + nbw1 + 1 + nhb, 256, 0, stream>>>(
        x, (uint32*)xh, n4, W1l, W1r, W1t, W2l, W2r, Wlin, b2, fw, fc,
        dst, bcount, E, nbx, nbw1, nhb);

    // bucket scan + scatter into bucket-ordered records
    bucket_scan_kernel<<<1, 256, 0, stream>>>(bcount, bbase, bcursor, NBUCK);
    scatter_kernel<<<nsb, 256, 0, stream>>>(src, dst, bcursor, recs, E, nsb);

    // layer 1: bucket-local aggregation, then MFMA GEMM with fused GEMV
    agg1_bucket_kernel<<<NBUCK, 256, 0, stream>>>((const uint32*)xh, recs, bbase,
                                                  (uint32*)meanh, invdeg, N);
    gemm1_mfma_kernel<<<(N + 63) / 64, 256, 0, stream>>>(meanh, xh, W1t, b1, fw,
                                                         pab, quv, N);

    // folded layer 2: bucket-local scalar aggregation
    agg_link_kernel<<<NBUCK, 256, 0, stream>>>(pab, quv, recs, bbase, invdeg, fc,
                                               za, zb, N);

    // link prediction
    link_kernel<<<(P + 255) / 256, 256, 0, stream>>>(za, zb, ps, pd, blin, out, P);
}

// Round 10
// 237.736 us; speedup vs baseline: 3.7423x; 3.7423x over previous
//
#include <hip/hip_runtime.h>
#include <math.h>

// ---------------------------------------------------------------------------
// 2-layer GraphSAGE (mean aggr) + link predictor. bf16 MFMA, folded layer 2.
// CSR built via bucket scatter + per-bucket counting sort (int LDS atomics
// only — fp32 LDS atomicAdd is a CAS loop on HIP, never use it).
//
//   prep: cast x->bf16 | W1->W1t bf16 | fold W2/Wlin/b2 | bucket hist (LDS int)
//   bucket_scan (1 block) -> scatter (dense bucket-ordered 4B records)
//   sort: per-bucket counting sort -> node-ordered esrc(ushort) + rowptr
//   agg1: meanh = mean_j xh_j            (register-accum gather, 8-wide MLP)
//   gemm1+gemv: h=relu([meanh|xh]@W1+b1) in-reg, dot folded vecs -> pab,quv
//   agg_link: za,zb per node             (8B/edge gather, 4-wide MLP)
//   link: sigmoid(za[ps]+zb[pd]+blin)
// ---------------------------------------------------------------------------

typedef __attribute__((ext_vector_type(8))) short bf16x8;
typedef __attribute__((ext_vector_type(4))) float f32x4;
typedef unsigned int uint32;
typedef unsigned short ushort16;

#define MAXBUCK 784   // buckets of 64 nodes; N<=50176
#define BPAD 16       // bucket counter stride (64B) to avoid same-line atomics

__device__ __forceinline__ ushort16 f2bf(float f) {
    uint32 u = __float_as_uint(f);
    uint32 r = u + 0x7FFFu + ((u >> 16) & 1u);   // round-to-nearest-even
    return (ushort16)(r >> 16);
}

// ---- fused prep: cast_x | cast_w1 | fold_w2 | bucket hist ------------------

__global__ __launch_bounds__(256)
void prep_kernel(const float* __restrict__ x, uint32* __restrict__ xh, long long n4,
                 const float* __restrict__ W1l, const float* __restrict__ W1r,
                 ushort16* __restrict__ W1t,
                 const float* __restrict__ W2l, const float* __restrict__ W2r,
                 const float* __restrict__ Wlin, const float* __restrict__ b2,
                 float* __restrict__ fw, float* __restrict__ fc,
                 const int* __restrict__ dst, int* __restrict__ bcountP, int E,
                 int nbx, int nbw1, int nhb) {
    __shared__ int lh[MAXBUCK];
    int b = blockIdx.x;
    int t = threadIdx.x;
    if (b < nbx) {
        long long i = (long long)b * 256 + t;
        if (i < n4) {
            float4 v = ((const float4*)x)[i];
            uint2 o;
            o.x = (uint32)f2bf(v.x) | ((uint32)f2bf(v.y) << 16);
            o.y = (uint32)f2bf(v.z) | ((uint32)f2bf(v.w) << 16);
            ((uint2*)xh)[i] = o;
        }
    } else if (b < nbx + nbw1) {
        int idx = (b - nbx) * 256 + t;            // 32768: W1t[n][k], k<128->W1l
        int n = idx >> 8, k = idx & 255;
        float v = (k < 128) ? W1l[k * 128 + n] : W1r[(k - 128) * 128 + n];
        W1t[n * 256 + k] = f2bf(v);
    } else if (b == nbx + nbw1) {
        // fold layer-2 weights with link weights: fw = [va|vc|vbp|vd]
        if (t < 128) {
            float a = 0.f, c = 0.f;
            for (int l = 0; l < 64; ++l) {
                float w = W2l[t * 64 + l];
                a += w * Wlin[l];
                c += w * Wlin[64 + l];
            }
            fw[t] = a; fw[128 + t] = c;
        } else {
            int k = t - 128;
            float a = 0.f, c = 0.f;
            for (int l = 0; l < 64; ++l) {
                float w = W2r[k * 64 + l];
                a += w * Wlin[l];
                c += w * Wlin[64 + l];
            }
            fw[256 + k] = a; fw[384 + k] = c;
        }
        if (t == 0) { float s = 0.f; for (int l = 0; l < 64; ++l) s += b2[l] * Wlin[l];      fc[0] = s; }
        if (t == 1) { float s = 0.f; for (int l = 0; l < 64; ++l) s += b2[l] * Wlin[64 + l]; fc[1] = s; }
    } else {
        int hb = b - nbx - nbw1 - 1;              // 0..nhb-1
        for (int i = t; i < MAXBUCK; i += 256) lh[i] = 0;
        __syncthreads();
        int per = (E + nhb - 1) / nhb;
        int e0 = hb * per, e1 = min(e0 + per, E);
        for (int e = e0 + t; e < e1; e += 256) atomicAdd(&lh[dst[e] >> 6], 1);
        __syncthreads();
        for (int i = t; i < MAXBUCK; i += 256)
            if (lh[i]) atomicAdd(&bcountP[i * BPAD], lh[i]);
    }
}

// ---- bucket scan (1 block) -------------------------------------------------

__global__ void bucket_scan_kernel(const int* __restrict__ bcountP,
                                   int* __restrict__ bbase,
                                   int* __restrict__ bcursorP, int nbuck) {
    __shared__ int part[256];
    int t = threadIdx.x;
    int lo = t * 4;
    int hi = min(lo + 4, nbuck);
    int loc[4];
    int s = 0;
    for (int i = lo; i < hi; ++i) { loc[i - lo] = bcountP[i * BPAD]; s += loc[i - lo]; }
    part[t] = s;
    __syncthreads();
    for (int off = 1; off < 256; off <<= 1) {
        int v = (t >= off) ? part[t - off] : 0;
        __syncthreads();
        part[t] += v;
        __syncthreads();
    }
    int run = (t == 0) ? 0 : part[t - 1];
    for (int i = lo; i < hi; ++i) {
        bbase[i] = run; bcursorP[i * BPAD] = run; run += loc[i - lo];
    }
    if (t == 255) bbase[nbuck] = part[255];
}

// ---- scatter edges into bucket-ordered 4B records --------------------------
// record = src | (dst&63)<<16 ; per-(block,bucket) runs are dense

__global__ __launch_bounds__(256)
void scatter_kernel(const int* __restrict__ src, const int* __restrict__ dst,
                    int* __restrict__ bcursorP, uint32* __restrict__ recs,
                    int E, int nsb) {
    __shared__ int lh[MAXBUCK];
    __shared__ int lb[MAXBUCK];
    int t = threadIdx.x;
    int per = (E + nsb - 1) / nsb;
    int e0 = blockIdx.x * per, e1 = min(e0 + per, E);
    for (int i = t; i < MAXBUCK; i += 256) lh[i] = 0;
    __syncthreads();
    for (int e = e0 + t; e < e1; e += 256) atomicAdd(&lh[dst[e] >> 6], 1);
    __syncthreads();
    for (int i = t; i < MAXBUCK; i += 256) {
        int c = lh[i];
        lb[i] = c ? atomicAdd(&bcursorP[i * BPAD], c) : 0;
    }
    __syncthreads();
    for (int i = t; i < MAXBUCK; i += 256) lh[i] = 0;
    __syncthreads();
    for (int e = e0 + t; e < e1; e += 256) {
        int d = dst[e];
        int b = d >> 6;
        int r = atomicAdd(&lh[b], 1);
        recs[lb[b] + r] = (uint32)src[e] | ((uint32)(d & 63) << 16);
    }
}

// ---- per-bucket counting sort: recs -> node-ordered esrc + rowptr ----------

__global__ __launch_bounds__(256)
void sort_kernel(const uint32* __restrict__ recs, const int* __restrict__ bbase,
                 int* __restrict__ rowptr, ushort16* __restrict__ esrc,
                 int N, int E) {
    __shared__ int lh[64];
    int b = blockIdx.x;
    int t = threadIdx.x;
    int s0 = bbase[b], s1 = bbase[b + 1];
    if (t < 64) lh[t] = 0;
    __syncthreads();
    for (int i = s0 + t; i < s1; i += 256)
        atomicAdd(&lh[recs[i] >> 16], 1);
    __syncthreads();
    if (t < 64) {
        int v = lh[t];
        int incl = v;
        #pragma unroll
        for (int off = 1; off < 64; off <<= 1) {
            int u = __shfl_up(incl, off, 64);
            if (t >= off) incl += u;
        }
        int excl = incl - v;
        int node = b * 64 + t;
        if (node < N) rowptr[node] = s0 + excl;
        lh[t] = excl;                    // becomes local cursor
    }
    __syncthreads();
    for (int i = s0 + t; i < s1; i += 256) {
        uint32 r = recs[i];
        int pos = atomicAdd(&lh[r >> 16], 1);
        esrc[s0 + pos] = (ushort16)(r & 0xFFFFu);
    }
    if (b == 0 && t == 0) rowptr[N] = E;
}

// ---- layer-1 aggregation (bf16 gather, register accum, 8-wide MLP) ---------

__global__ void agg_mean_x_kernel(const uint32* __restrict__ xh,
                                  const int* __restrict__ rowptr,
                                  const ushort16* __restrict__ esrc,
                                  uint32* __restrict__ meanh, int N) {
    int node = blockIdx.x * 4 + (threadIdx.x >> 6);
    int lane = threadIdx.x & 63;
    if (node >= N) return;
    int s0 = rowptr[node], s1 = rowptr[node + 1];
    if (s0 == s1) { meanh[(size_t)node * 64 + lane] = 0u; return; }
    float ax[8] = {}, ay[8] = {};
    for (int k = s0; k < s1; k += 8) {
        int idx[8]; float msk[8];
        #pragma unroll
        for (int j = 0; j < 8; ++j) {
            int kj = k + j;
            idx[j] = esrc[kj < s1 ? kj : k];
            msk[j] = (kj < s1) ? 1.f : 0.f;
        }
        #pragma unroll
        for (int j = 0; j < 8; ++j) {
            uint32 v = xh[(size_t)idx[j] * 64 + lane];
            ax[j] += __uint_as_float(v << 16) * msk[j];
            ay[j] += __uint_as_float(v & 0xFFFF0000u) * msk[j];
        }
    }
    float inv = 1.0f / (float)(s1 - s0);
    float sx = ((ax[0] + ax[1]) + (ax[2] + ax[3])) + ((ax[4] + ax[5]) + (ax[6] + ax[7]));
    float sy = ((ay[0] + ay[1]) + (ay[2] + ay[3])) + ((ay[4] + ay[5]) + (ay[6] + ay[7]));
    meanh[(size_t)node * 64 + lane] = (uint32)f2bf(sx * inv) | ((uint32)f2bf(sy * inv) << 16);
}

// ---- MFMA GEMM1 + fused GEMV epilogue --------------------------------------
// Per-wave 16 rows x 128 cols, 8 MFMA 16x16x32. h in registers only.
// A-frag: A[m=lane&15][k=quad*8+j]; D: row=quad*4+r, col=lane&15 (m89/m91).

__global__ __launch_bounds__(256)
void gemm1_mfma_kernel(const ushort16* __restrict__ meanh,
                       const ushort16* __restrict__ xh,
                       const ushort16* __restrict__ W1t,
                       const float* __restrict__ b1,
                       const float* __restrict__ fw,
                       float2* __restrict__ pab, float2* __restrict__ quv, int N) {
    int wave = threadIdx.x >> 6;
    int lane = threadIdx.x & 63;
    int m = lane & 15;
    int quad = lane >> 4;
    int row0 = blockIdx.x * 64 + wave * 16;
    int arow = row0 + m; if (arow > N - 1) arow = N - 1;
    f32x4 acc[8];
    #pragma unroll
    for (int c = 0; c < 8; ++c) acc[c] = (f32x4){0.f, 0.f, 0.f, 0.f};
    #pragma unroll
    for (int ks = 0; ks < 8; ++ks) {
        int k0 = ks * 32;
        const ushort16* Ab = (ks < 4) ? meanh : xh;
        bf16x8 a = *(const bf16x8*)(Ab + (size_t)arow * 128 + (k0 & 127) + quad * 8);
        #pragma unroll
        for (int c = 0; c < 8; ++c) {
            bf16x8 b = *(const bf16x8*)(W1t + (size_t)(c * 16 + m) * 256 + k0 + quad * 8);
            acc[c] = __builtin_amdgcn_mfma_f32_16x16x32_bf16(a, b, acc[c], 0, 0, 0);
        }
    }
    float da[4] = {}, dc[4] = {}, db[4] = {}, dd[4] = {};
    #pragma unroll
    for (int c = 0; c < 8; ++c) {
        int col = c * 16 + m;
        float bias = b1[col];
        float wa = fw[col], wc = fw[128 + col], wb = fw[256 + col], wd = fw[384 + col];
        #pragma unroll
        for (int r = 0; r < 4; ++r) {
            float v = fmaxf(acc[c][r] + bias, 0.f);
            da[r] += v * wa; dc[r] += v * wc; db[r] += v * wb; dd[r] += v * wd;
        }
    }
    #pragma unroll
    for (int r = 0; r < 4; ++r) {
        #pragma unroll
        for (int msk = 1; msk < 16; msk <<= 1) {
            da[r] += __shfl_xor(da[r], msk, 64);
            dc[r] += __shfl_xor(dc[r], msk, 64);
            db[r] += __shfl_xor(db[r], msk, 64);
            dd[r] += __shfl_xor(dd[r], msk, 64);
        }
    }
    if (m == 0) {
        #pragma unroll
        for (int r = 0; r < 4; ++r) {
            int grow = row0 + quad * 4 + r;
            if (grow < N) {
                pab[grow] = make_float2(da[r], dc[r]);
                quv[grow] = make_float2(db[r], dd[r]);
            }
        }
    }
}

// ---- layer-2 aggregation on folded scalars (thread/node, 4-wide MLP) -------

__global__ void agg_link_kernel(const float2* __restrict__ pab,
                                const float2* __restrict__ quv,
                                const int* __restrict__ rowptr,
                                const ushort16* __restrict__ esrc,
                                const float* __restrict__ fc,
                                float* __restrict__ za, float* __restrict__ zb, int N) {
    int i = blockIdx.x * blockDim.x + threadIdx.x;
    if (i >= N) return;
    int s0 = rowptr[i], s1 = rowptr[i + 1];
    float a0 = 0.f, a1 = 0.f, a2 = 0.f, a3 = 0.f;
    float c0 = 0.f, c1 = 0.f, c2 = 0.f, c3 = 0.f;
    for (int k = s0; k < s1; k += 4) {
        int k1 = k + 1, k2 = k + 2, k3 = k + 3;
        int i0 = esrc[k];
        int i1 = esrc[k1 < s1 ? k1 : k];
        int i2 = esrc[k2 < s1 ? k2 : k];
        int i3 = esrc[k3 < s1 ? k3 : k];
        float m1 = (k1 < s1) ? 1.f : 0.f;
        float m2 = (k2 < s1) ? 1.f : 0.f;
        float m3 = (k3 < s1) ? 1.f : 0.f;
        float2 p0 = pab[i0], p1 = pab[i1], p2 = pab[i2], p3 = pab[i3];
        a0 += p0.x;      c0 += p0.y;
        a1 += p1.x * m1; c1 += p1.y * m1;
        a2 += p2.x * m2; c2 += p2.y * m2;
        a3 += p3.x * m3; c3 += p3.y * m3;
    }
    float spa = (a0 + a1) + (a2 + a3);
    float spc = (c0 + c1) + (c2 + c3);
    float inv = (s1 > s0) ? 1.0f / (float)(s1 - s0) : 0.f;
    float2 q = quv[i];
    za[i] = spa * inv + q.x + fc[0];
    zb[i] = spc * inv + q.y + fc[1];
}

// ---- link prediction: out[p] = sigmoid(za[ps] + zb[pd] + blin) -------------

__global__ void link_kernel(const float* __restrict__ za, const float* __restrict__ zb,
                            const int* __restrict__ ps, const int* __restrict__ pd,
                            const float* __restrict__ blin,
                            float* __restrict__ out, int P) {
    int p = blockIdx.x * blockDim.x + threadIdx.x;
    if (p >= P) return;
    float logit = za[ps[p]] + zb[pd[p]] + blin[0];
    out[p] = 1.0f / (1.0f + expf(-logit));
}

// ---------------------------------------------------------------------------

extern "C" void kernel_launch(void* const* d_in, const int* in_sizes, int n_in,
                              void* d_out, int out_size, void* d_ws, size_t ws_size,
                              hipStream_t stream) {
    const float* x          = (const float*)d_in[0];
    const int*   edge_index = (const int*)d_in[1];
    const int*   edge_pairs = (const int*)d_in[2];
    const float* W1l        = (const float*)d_in[3];
    const float* b1         = (const float*)d_in[4];
    const float* W1r        = (const float*)d_in[5];
    const float* W2l        = (const float*)d_in[6];
    const float* b2         = (const float*)d_in[7];
    const float* W2r        = (const float*)d_in[8];
    const float* Wlin       = (const float*)d_in[9];
    const float* blin       = (const float*)d_in[10];
    float* out = (float*)d_out;

    const int N = in_sizes[0] / 128;       // 50000
    const int E = in_sizes[1] / 2;         // 800000
    const int P = in_sizes[2] / 2;         // 200000
    const int NBUCK = (N + 63) >> 6;       // 782

    const int* src = edge_index;
    const int* dst = edge_index + E;
    const int* ps  = edge_pairs;
    const int* pd  = edge_pairs + P;

    // workspace layout
    ushort16* xh    = (ushort16*)d_ws;                 // N*128 bf16
    ushort16* meanh = xh + (size_t)N * 128;            // N*128 bf16
    ushort16* W1t   = meanh + (size_t)N * 128;         // 128*256 bf16
    float* fw      = (float*)(W1t + 128 * 256);        // 512 f32
    float* fc      = fw + 512;                         // 2 f32 (+2 pad)
    float2* pab    = (float2*)(fc + 4);                // N float2
    float2* quv    = pab + N;                          // N float2
    float* za      = (float*)(quv + N);                // N f32
    float* zb      = za + N;                           // N f32
    int* bbase     = (int*)(zb + N);                   // NBUCK+1
    int* bcountP   = bbase + (MAXBUCK + 16);           // MAXBUCK*BPAD
    int* bcursorP  = bcountP + MAXBUCK * BPAD;         // MAXBUCK*BPAD
    int* rowptr    = bcursorP + MAXBUCK * BPAD;        // N+1
    uint32* recs   = (uint32*)(rowptr + N + 16);       // E records
    ushort16* esrc = (ushort16*)(recs + E);            // E ushort

    const long long n4 = (long long)N * 128 / 4;       // 1.6M
    const int nbx  = (int)((n4 + 255) / 256);          // 6250
    const int nbw1 = 128;
    const int nhb  = 64;                               // bucket-hist blocks
    const int nsb  = 64;                               // scatter blocks

    hipMemsetAsync(bcountP, 0, (size_t)MAXBUCK * BPAD * sizeof(int), stream);

    // fused prep: cast x, cast+transpose W1, fold W2/Wlin/b2, bucket histogram
    prep_kernel<<<nbx + nbw1 + 1 + nhb, 256, 0, stream>>>(
        x, (uint32*)xh, n4, W1l, W1r, W1t, W2l, W2r, Wlin, b2, fw, fc,
        dst, bcountP, E, nbx, nbw1, nhb);

    // bucket scan -> dense bucket-ordered scatter -> per-bucket counting sort
    bucket_scan_kernel<<<1, 256, 0, stream>>>(bcountP, bbase, bcursorP, NBUCK);
    scatter_kernel<<<nsb, 256, 0, stream>>>(src, dst, bcursorP, recs, E, nsb);
    sort_kernel<<<NBUCK, 256, 0, stream>>>(recs, bbase, rowptr, esrc, N, E);

    // layer 1: gather aggregation + MFMA GEMM with fused GEMV
    agg_mean_x_kernel<<<(N + 3) / 4, 256, 0, stream>>>((const uint32*)xh, rowptr, esrc,
                                                       (uint32*)meanh, N);
    gemm1_mfma_kernel<<<(N + 63) / 64, 256, 0, stream>>>(meanh, xh, W1t, b1, fw,
                                                         pab, quv, N);

    // folded layer 2: scalar gather aggregation
    agg_link_kernel<<<(N + 255) / 256, 256, 0, stream>>>(pab, quv, rowptr, esrc, fc,
                                                         za, zb, N);

    // link prediction
    link_kernel<<<(P + 255) / 256, 256, 0, stream>>>(za, zb, ps, pd, blin, out, P);
}

// Round 11
// 224.221 us; speedup vs baseline: 3.9679x; 1.0603x over previous
//
#include <hip/hip_runtime.h>
#include <math.h>

// ---------------------------------------------------------------------------
// 2-layer GraphSAGE (mean aggr) + link predictor. bf16 MFMA, folded layer 2.
// CSR built via bucket scatter + per-bucket counting sort (int LDS atomics
// only — fp32 LDS atomicAdd is a CAS loop on HIP, never use it).
//
//   prep: cast x->bf16 | W1->W1t bf16 | fold W2/Wlin/b2 | bucket hist (LDS int)
//   bucket_scan (1 block) -> scatter (512 blocks; recs L2-resident so store
//     order doesn't matter, parallelism does) -> per-bucket counting sort
//   agg1: meanh = mean_j xh_j            (register-accum gather, 8-wide MLP)
//   gemm1+gemv: h=relu([meanh|xh]@W1+b1) in-reg, dot folded vecs -> pab,quv
//   agg_link: za,zb per node             (8B/edge gather, 4-wide MLP)
//   link: sigmoid(za[ps]+zb[pd]+blin)
// ---------------------------------------------------------------------------

typedef __attribute__((ext_vector_type(8))) short bf16x8;
typedef __attribute__((ext_vector_type(4))) float f32x4;
typedef unsigned int uint32;
typedef unsigned short ushort16;

#define MAXBUCK 784   // buckets of 64 nodes; N<=50176
#define BPAD 16       // bucket counter stride (64B) to avoid same-line atomics

__device__ __forceinline__ ushort16 f2bf(float f) {
    uint32 u = __float_as_uint(f);
    uint32 r = u + 0x7FFFu + ((u >> 16) & 1u);   // round-to-nearest-even
    return (ushort16)(r >> 16);
}

// ---- fused prep: cast_x | cast_w1 | fold_w2 | bucket hist ------------------

__global__ __launch_bounds__(256)
void prep_kernel(const float* __restrict__ x, uint32* __restrict__ xh, long long n4,
                 const float* __restrict__ W1l, const float* __restrict__ W1r,
                 ushort16* __restrict__ W1t,
                 const float* __restrict__ W2l, const float* __restrict__ W2r,
                 const float* __restrict__ Wlin, const float* __restrict__ b2,
                 float* __restrict__ fw, float* __restrict__ fc,
                 const int* __restrict__ dst, int* __restrict__ bcountP, int E,
                 int nbx, int nbw1, int nhb) {
    __shared__ int lh[MAXBUCK];
    int b = blockIdx.x;
    int t = threadIdx.x;
    if (b < nbx) {
        long long i = (long long)b * 256 + t;
        if (i < n4) {
            float4 v = ((const float4*)x)[i];
            uint2 o;
            o.x = (uint32)f2bf(v.x) | ((uint32)f2bf(v.y) << 16);
            o.y = (uint32)f2bf(v.z) | ((uint32)f2bf(v.w) << 16);
            ((uint2*)xh)[i] = o;
        }
    } else if (b < nbx + nbw1) {
        int idx = (b - nbx) * 256 + t;            // 32768: W1t[n][k], k<128->W1l
        int n = idx >> 8, k = idx & 255;
        float v = (k < 128) ? W1l[k * 128 + n] : W1r[(k - 128) * 128 + n];
        W1t[n * 256 + k] = f2bf(v);
    } else if (b == nbx + nbw1) {
        // fold layer-2 weights with link weights: fw = [va|vc|vbp|vd]
        if (t < 128) {
            float a = 0.f, c = 0.f;
            for (int l = 0; l < 64; ++l) {
                float w = W2l[t * 64 + l];
                a += w * Wlin[l];
                c += w * Wlin[64 + l];
            }
            fw[t] = a; fw[128 + t] = c;
        } else {
            int k = t - 128;
            float a = 0.f, c = 0.f;
            for (int l = 0; l < 64; ++l) {
                float w = W2r[k * 64 + l];
                a += w * Wlin[l];
                c += w * Wlin[64 + l];
            }
            fw[256 + k] = a; fw[384 + k] = c;
        }
        if (t == 0) { float s = 0.f; for (int l = 0; l < 64; ++l) s += b2[l] * Wlin[l];      fc[0] = s; }
        if (t == 1) { float s = 0.f; for (int l = 0; l < 64; ++l) s += b2[l] * Wlin[64 + l]; fc[1] = s; }
    } else {
        int hb = b - nbx - nbw1 - 1;              // 0..nhb-1
        for (int i = t; i < MAXBUCK; i += 256) lh[i] = 0;
        __syncthreads();
        int per = (E + nhb - 1) / nhb;
        int e0 = hb * per, e1 = min(e0 + per, E);
        for (int e = e0 + t; e < e1; e += 256) atomicAdd(&lh[dst[e] >> 6], 1);
        __syncthreads();
        for (int i = t; i < MAXBUCK; i += 256)
            if (lh[i]) atomicAdd(&bcountP[i * BPAD], lh[i]);
    }
}

// ---- bucket scan (1 block) -------------------------------------------------

__global__ void bucket_scan_kernel(const int* __restrict__ bcountP,
                                   int* __restrict__ bbase,
                                   int* __restrict__ bcursorP, int nbuck) {
    __shared__ int part[256];
    int t = threadIdx.x;
    int lo = t * 4;
    int hi = min(lo + 4, nbuck);
    int loc[4];
    int s = 0;
    for (int i = lo; i < hi; ++i) { loc[i - lo] = bcountP[i * BPAD]; s += loc[i - lo]; }
    part[t] = s;
    __syncthreads();
    for (int off = 1; off < 256; off <<= 1) {
        int v = (t >= off) ? part[t - off] : 0;
        __syncthreads();
        part[t] += v;
        __syncthreads();
    }
    int run = (t == 0) ? 0 : part[t - 1];
    for (int i = lo; i < hi; ++i) {
        bbase[i] = run; bcursorP[i * BPAD] = run; run += loc[i - lo];
    }
    if (t == 255) bbase[nbuck] = part[255];
}

// ---- scatter edges into bucket-ordered 4B records --------------------------
// record = src | (dst&63)<<16 ; recs is L2-resident so lines write back once

__global__ __launch_bounds__(256)
void scatter_kernel(const int* __restrict__ src, const int* __restrict__ dst,
                    int* __restrict__ bcursorP, uint32* __restrict__ recs,
                    int E, int nsb) {
    __shared__ int lh[MAXBUCK];
    __shared__ int lb[MAXBUCK];
    int t = threadIdx.x;
    int per = (E + nsb - 1) / nsb;
    int e0 = blockIdx.x * per, e1 = min(e0 + per, E);
    for (int i = t; i < MAXBUCK; i += 256) lh[i] = 0;
    __syncthreads();
    for (int e = e0 + t; e < e1; e += 256) atomicAdd(&lh[dst[e] >> 6], 1);
    __syncthreads();
    for (int i = t; i < MAXBUCK; i += 256) {
        int c = lh[i];
        lb[i] = c ? atomicAdd(&bcursorP[i * BPAD], c) : 0;
    }
    __syncthreads();
    for (int i = t; i < MAXBUCK; i += 256) lh[i] = 0;
    __syncthreads();
    for (int e = e0 + t; e < e1; e += 256) {
        int d = dst[e];
        int b = d >> 6;
        int r = atomicAdd(&lh[b], 1);
        recs[lb[b] + r] = (uint32)src[e] | ((uint32)(d & 63) << 16);
    }
}

// ---- per-bucket counting sort: recs -> node-ordered esrc + rowptr ----------

__global__ __launch_bounds__(256)
void sort_kernel(const uint32* __restrict__ recs, const int* __restrict__ bbase,
                 int* __restrict__ rowptr, ushort16* __restrict__ esrc,
                 int N, int E) {
    __shared__ int lh[64];
    int b = blockIdx.x;
    int t = threadIdx.x;
    int s0 = bbase[b], s1 = bbase[b + 1];
    if (t < 64) lh[t] = 0;
    __syncthreads();
    for (int i = s0 + t; i < s1; i += 256)
        atomicAdd(&lh[recs[i] >> 16], 1);
    __syncthreads();
    if (t < 64) {
        int v = lh[t];
        int incl = v;
        #pragma unroll
        for (int off = 1; off < 64; off <<= 1) {
            int u = __shfl_up(incl, off, 64);
            if (t >= off) incl += u;
        }
        int excl = incl - v;
        int node = b * 64 + t;
        if (node < N) rowptr[node] = s0 + excl;
        lh[t] = excl;                    // becomes local cursor
    }
    __syncthreads();
    for (int i = s0 + t; i < s1; i += 256) {
        uint32 r = recs[i];
        int pos = atomicAdd(&lh[r >> 16], 1);
        esrc[s0 + pos] = (ushort16)(r & 0xFFFFu);
    }
    if (b == 0 && t == 0) rowptr[N] = E;
}

// ---- layer-1 aggregation (bf16 gather, register accum, 8-wide MLP) ---------

__global__ void agg_mean_x_kernel(const uint32* __restrict__ xh,
                                  const int* __restrict__ rowptr,
                                  const ushort16* __restrict__ esrc,
                                  uint32* __restrict__ meanh, int N) {
    int node = blockIdx.x * 4 + (threadIdx.x >> 6);
    int lane = threadIdx.x & 63;
    if (node >= N) return;
    int s0 = rowptr[node], s1 = rowptr[node + 1];
    if (s0 == s1) { meanh[(size_t)node * 64 + lane] = 0u; return; }
    float ax[8] = {}, ay[8] = {};
    for (int k = s0; k < s1; k += 8) {
        int idx[8]; float msk[8];
        #pragma unroll
        for (int j = 0; j < 8; ++j) {
            int kj = k + j;
            idx[j] = esrc[kj < s1 ? kj : k];
            msk[j] = (kj < s1) ? 1.f : 0.f;
        }
        #pragma unroll
        for (int j = 0; j < 8; ++j) {
            uint32 v = xh[(size_t)idx[j] * 64 + lane];
            ax[j] += __uint_as_float(v << 16) * msk[j];
            ay[j] += __uint_as_float(v & 0xFFFF0000u) * msk[j];
        }
    }
    float inv = 1.0f / (float)(s1 - s0);
    float sx = ((ax[0] + ax[1]) + (ax[2] + ax[3])) + ((ax[4] + ax[5]) + (ax[6] + ax[7]));
    float sy = ((ay[0] + ay[1]) + (ay[2] + ay[3])) + ((ay[4] + ay[5]) + (ay[6] + ay[7]));
    meanh[(size_t)node * 64 + lane] = (uint32)f2bf(sx * inv) | ((uint32)f2bf(sy * inv) << 16);
}

// ---- MFMA GEMM1 + fused GEMV epilogue --------------------------------------
// Per-wave 16 rows x 128 cols, 8 MFMA 16x16x32. h in registers only.
// A-frag: A[m=lane&15][k=quad*8+j]; D: row=quad*4+r, col=lane&15 (m89/m91).

__global__ __launch_bounds__(256)
void gemm1_mfma_kernel(const ushort16* __restrict__ meanh,
                       const ushort16* __restrict__ xh,
                       const ushort16* __restrict__ W1t,
                       const float* __restrict__ b1,
                       const float* __restrict__ fw,
                       float2* __restrict__ pab, float2* __restrict__ quv, int N) {
    int wave = threadIdx.x >> 6;
    int lane = threadIdx.x & 63;
    int m = lane & 15;
    int quad = lane >> 4;
    int row0 = blockIdx.x * 64 + wave * 16;
    int arow = row0 + m; if (arow > N - 1) arow = N - 1;
    f32x4 acc[8];
    #pragma unroll
    for (int c = 0; c < 8; ++c) acc[c] = (f32x4){0.f, 0.f, 0.f, 0.f};
    #pragma unroll
    for (int ks = 0; ks < 8; ++ks) {
        int k0 = ks * 32;
        const ushort16* Ab = (ks < 4) ? meanh : xh;
        bf16x8 a = *(const bf16x8*)(Ab + (size_t)arow * 128 + (k0 & 127) + quad * 8);
        #pragma unroll
        for (int c = 0; c < 8; ++c) {
            bf16x8 b = *(const bf16x8*)(W1t + (size_t)(c * 16 + m) * 256 + k0 + quad * 8);
            acc[c] = __builtin_amdgcn_mfma_f32_16x16x32_bf16(a, b, acc[c], 0, 0, 0);
        }
    }
    float da[4] = {}, dc[4] = {}, db[4] = {}, dd[4] = {};
    #pragma unroll
    for (int c = 0; c < 8; ++c) {
        int col = c * 16 + m;
        float bias = b1[col];
        float wa = fw[col], wc = fw[128 + col], wb = fw[256 + col], wd = fw[384 + col];
        #pragma unroll
        for (int r = 0; r < 4; ++r) {
            float v = fmaxf(acc[c][r] + bias, 0.f);
            da[r] += v * wa; dc[r] += v * wc; db[r] += v * wb; dd[r] += v * wd;
        }
    }
    #pragma unroll
    for (int r = 0; r < 4; ++r) {
        #pragma unroll
        for (int msk = 1; msk < 16; msk <<= 1) {
            da[r] += __shfl_xor(da[r], msk, 64);
            dc[r] += __shfl_xor(dc[r], msk, 64);
            db[r] += __shfl_xor(db[r], msk, 64);
            dd[r] += __shfl_xor(dd[r], msk, 64);
        }
    }
    if (m == 0) {
        #pragma unroll
        for (int r = 0; r < 4; ++r) {
            int grow = row0 + quad * 4 + r;
            if (grow < N) {
                pab[grow] = make_float2(da[r], dc[r]);
                quv[grow] = make_float2(db[r], dd[r]);
            }
        }
    }
}

// ---- layer-2 aggregation on folded scalars (thread/node, 4-wide MLP) -------

__global__ void agg_link_kernel(const float2* __restrict__ pab,
                                const float2* __restrict__ quv,
                                const int* __restrict__ rowptr,
                                const ushort16* __restrict__ esrc,
                                const float* __restrict__ fc,
                                float* __restrict__ za, float* __restrict__ zb, int N) {
    int i = blockIdx.x * blockDim.x + threadIdx.x;
    if (i >= N) return;
    int s0 = rowptr[i], s1 = rowptr[i + 1];
    float a0 = 0.f, a1 = 0.f, a2 = 0.f, a3 = 0.f;
    float c0 = 0.f, c1 = 0.f, c2 = 0.f, c3 = 0.f;
    for (int k = s0; k < s1; k += 4) {
        int k1 = k + 1, k2 = k + 2, k3 = k + 3;
        int i0 = esrc[k];
        int i1 = esrc[k1 < s1 ? k1 : k];
        int i2 = esrc[k2 < s1 ? k2 : k];
        int i3 = esrc[k3 < s1 ? k3 : k];
        float m1 = (k1 < s1) ? 1.f : 0.f;
        float m2 = (k2 < s1) ? 1.f : 0.f;
        float m3 = (k3 < s1) ? 1.f : 0.f;
        float2 p0 = pab[i0], p1 = pab[i1], p2 = pab[i2], p3 = pab[i3];
        a0 += p0.x;      c0 += p0.y;
        a1 += p1.x * m1; c1 += p1.y * m1;
        a2 += p2.x * m2; c2 += p2.y * m2;
        a3 += p3.x * m3; c3 += p3.y * m3;
    }
    float spa = (a0 + a1) + (a2 + a3);
    float spc = (c0 + c1) + (c2 + c3);
    float inv = (s1 > s0) ? 1.0f / (float)(s1 - s0) : 0.f;
    float2 q = quv[i];
    za[i] = spa * inv + q.x + fc[0];
    zb[i] = spc * inv + q.y + fc[1];
}

// ---- link prediction: out[p] = sigmoid(za[ps] + zb[pd] + blin) -------------

__global__ void link_kernel(const float* __restrict__ za, const float* __restrict__ zb,
                            const int* __restrict__ ps, const int* __restrict__ pd,
                            const float* __restrict__ blin,
                            float* __restrict__ out, int P) {
    int p = blockIdx.x * blockDim.x + threadIdx.x;
    if (p >= P) return;
    float logit = za[ps[p]] + zb[pd[p]] + blin[0];
    out[p] = 1.0f / (1.0f + expf(-logit));
}

// ---------------------------------------------------------------------------

extern "C" void kernel_launch(void* const* d_in, const int* in_sizes, int n_in,
                              void* d_out, int out_size, void* d_ws, size_t ws_size,
                              hipStream_t stream) {
    const float* x          = (const float*)d_in[0];
    const int*   edge_index = (const int*)d_in[1];
    const int*   edge_pairs = (const int*)d_in[2];
    const float* W1l        = (const float*)d_in[3];
    const float* b1         = (const float*)d_in[4];
    const float* W1r        = (const float*)d_in[5];
    const float* W2l        = (const float*)d_in[6];
    const float* b2         = (const float*)d_in[7];
    const float* W2r        = (const float*)d_in[8];
    const float* Wlin       = (const float*)d_in[9];
    const float* blin       = (const float*)d_in[10];
    float* out = (float*)d_out;

    const int N = in_sizes[0] / 128;       // 50000
    const int E = in_sizes[1] / 2;         // 800000
    const int P = in_sizes[2] / 2;         // 200000
    const int NBUCK = (N + 63) >> 6;       // 782

    const int* src = edge_index;
    const int* dst = edge_index + E;
    const int* ps  = edge_pairs;
    const int* pd  = edge_pairs + P;

    // workspace layout
    ushort16* xh    = (ushort16*)d_ws;                 // N*128 bf16
    ushort16* meanh = xh + (size_t)N * 128;            // N*128 bf16
    ushort16* W1t   = meanh + (size_t)N * 128;         // 128*256 bf16
    float* fw      = (float*)(W1t + 128 * 256);        // 512 f32
    float* fc      = fw + 512;                         // 2 f32 (+2 pad)
    float2* pab    = (float2*)(fc + 4);                // N float2
    float2* quv    = pab + N;                          // N float2
    float* za      = (float*)(quv + N);                // N f32
    float* zb      = za + N;                           // N f32
    int* bbase     = (int*)(zb + N);                   // NBUCK+1
    int* bcountP   = bbase + (MAXBUCK + 16);           // MAXBUCK*BPAD
    int* bcursorP  = bcountP + MAXBUCK * BPAD;         // MAXBUCK*BPAD
    int* rowptr    = bcursorP + MAXBUCK * BPAD;        // N+1
    uint32* recs   = (uint32*)(rowptr + N + 16);       // E records
    ushort16* esrc = (ushort16*)(recs + E);            // E ushort

    const long long n4 = (long long)N * 128 / 4;       // 1.6M
    const int nbx  = (int)((n4 + 255) / 256);          // 6250
    const int nbw1 = 128;
    const int nhb  = 256;                              // bucket-hist blocks
    const int nsb  = 512;                              // scatter blocks (2/CU)

    hipMemsetAsync(bcountP, 0, (size_t)MAXBUCK * BPAD * sizeof(int), stream);

    // fused prep: cast x, cast+transpose W1, fold W2/Wlin/b2, bucket histogram
    prep_kernel<<<nbx + nbw1 + 1 + nhb, 256, 0, stream>>>(
        x, (uint32*)xh, n4, W1l, W1r, W1t, W2l, W2r, Wlin, b2, fw, fc,
        dst, bcountP, E, nbx, nbw1, nhb);

    // bucket scan -> bucket-ordered scatter -> per-bucket counting sort
    bucket_scan_kernel<<<1, 256, 0, stream>>>(bcountP, bbase, bcursorP, NBUCK);
    scatter_kernel<<<nsb, 256, 0, stream>>>(src, dst, bcursorP, recs, E, nsb);
    sort_kernel<<<NBUCK, 256, 0, stream>>>(recs, bbase, rowptr, esrc, N, E);

    // layer 1: gather aggregation + MFMA GEMM with fused GEMV
    agg_mean_x_kernel<<<(N + 3) / 4, 256, 0, stream>>>((const uint32*)xh, rowptr, esrc,
                                                       (uint32*)meanh, N);
    gemm1_mfma_kernel<<<(N + 63) / 64, 256, 0, stream>>>(meanh, xh, W1t, b1, fw,
                                                         pab, quv, N);

    // folded layer 2: scalar gather aggregation
    agg_link_kernel<<<(N + 255) / 256, 256, 0, stream>>>(pab, quv, rowptr, esrc, fc,
                                                         za, zb, N);

    // link prediction
    link_kernel<<<(P + 255) / 256, 256, 0, stream>>>(za, zb, ps, pd, blin, out, P);
}

// Round 12
// 196.020 us; speedup vs baseline: 4.5387x; 1.1439x over previous
//
#include <hip/hip_runtime.h>
#include <math.h>

// ---------------------------------------------------------------------------
// 2-layer GraphSAGE (mean aggr) + link predictor. bf16 MFMA, folded layer 2.
// Atomic-free bucketed CSR build (per-block histograms + shuffle-scan offsets;
// LDS int atomics only for intra-block ranks — fp32 LDS atomicAdd is a CAS
// loop on HIP, never use it).
//
//   prep: cast x->bf16 | W1->W1t bf16 | fold W2/Wlin/b2 | per-block hist
//   offs: per-bucket wave scan over block counts -> boff, tot
//   bucket_scan (1 block): scan tot -> bbase
//   scatter (512 blocks, no global atomics) -> per-bucket counting sort
//   agg1: meanh = mean_j xh_j            (register-accum gather, 16-wide MLP)
//   gemm1+gemv: h=relu([meanh|xh]@W1+b1) in-reg, dot folded vecs -> pab,quv
//   agg_link: za,zb per node             (8B/edge gather, 8-wide MLP)
//   link: sigmoid(za[ps]+zb[pd]+blin)
// ---------------------------------------------------------------------------

typedef __attribute__((ext_vector_type(8))) short bf16x8;
typedef __attribute__((ext_vector_type(4))) float f32x4;
typedef unsigned int uint32;
typedef unsigned short ushort16;

#define MAXBUCK 784   // buckets of 64 nodes; N<=50176
#define NHB 512       // hist/scatter blocks (must match between prep & scatter)

__device__ __forceinline__ ushort16 f2bf(float f) {
    uint32 u = __float_as_uint(f);
    uint32 r = u + 0x7FFFu + ((u >> 16) & 1u);   // round-to-nearest-even
    return (ushort16)(r >> 16);
}

// ---- fused prep: cast_x | cast_w1 | fold_w2 | per-block bucket hist --------

__global__ __launch_bounds__(256)
void prep_kernel(const float* __restrict__ x, uint32* __restrict__ xh, long long n4,
                 const float* __restrict__ W1l, const float* __restrict__ W1r,
                 ushort16* __restrict__ W1t,
                 const float* __restrict__ W2l, const float* __restrict__ W2r,
                 const float* __restrict__ Wlin, const float* __restrict__ b2,
                 float* __restrict__ fw, float* __restrict__ fc,
                 const int* __restrict__ dst, int* __restrict__ hcnt, int E,
                 int nbx, int nbw1) {
    __shared__ int lh[MAXBUCK];
    int b = blockIdx.x;
    int t = threadIdx.x;
    if (b < nbx) {
        long long i = (long long)b * 256 + t;
        if (i < n4) {
            float4 v = ((const float4*)x)[i];
            uint2 o;
            o.x = (uint32)f2bf(v.x) | ((uint32)f2bf(v.y) << 16);
            o.y = (uint32)f2bf(v.z) | ((uint32)f2bf(v.w) << 16);
            ((uint2*)xh)[i] = o;
        }
    } else if (b < nbx + nbw1) {
        int idx = (b - nbx) * 256 + t;            // 32768: W1t[n][k], k<128->W1l
        int n = idx >> 8, k = idx & 255;
        float v = (k < 128) ? W1l[k * 128 + n] : W1r[(k - 128) * 128 + n];
        W1t[n * 256 + k] = f2bf(v);
    } else if (b == nbx + nbw1) {
        // fold layer-2 weights with link weights: fw = [va|vc|vbp|vd]
        if (t < 128) {
            float a = 0.f, c = 0.f;
            for (int l = 0; l < 64; ++l) {
                float w = W2l[t * 64 + l];
                a += w * Wlin[l];
                c += w * Wlin[64 + l];
            }
            fw[t] = a; fw[128 + t] = c;
        } else {
            int k = t - 128;
            float a = 0.f, c = 0.f;
            for (int l = 0; l < 64; ++l) {
                float w = W2r[k * 64 + l];
                a += w * Wlin[l];
                c += w * Wlin[64 + l];
            }
            fw[256 + k] = a; fw[384 + k] = c;
        }
        if (t == 0) { float s = 0.f; for (int l = 0; l < 64; ++l) s += b2[l] * Wlin[l];      fc[0] = s; }
        if (t == 1) { float s = 0.f; for (int l = 0; l < 64; ++l) s += b2[l] * Wlin[64 + l]; fc[1] = s; }
    } else {
        int hb = b - nbx - nbw1 - 1;              // 0..NHB-1
        for (int i = t; i < MAXBUCK; i += 256) lh[i] = 0;
        __syncthreads();
        int per = (E + NHB - 1) / NHB;
        int e0 = hb * per, e1 = min(e0 + per, E);
        for (int e = e0 + t; e < e1; e += 256) atomicAdd(&lh[dst[e] >> 6], 1);
        __syncthreads();
        for (int i = t; i < MAXBUCK; i += 256)
            hcnt[hb * MAXBUCK + i] = lh[i];       // plain stores, zeros included
    }
}

// ---- per-bucket exclusive scan over block counts (wave per bucket) ---------
// boff[hb][k] = sum_{hb'<hb} hcnt[hb'][k]; tot[k] = column total

__global__ __launch_bounds__(256)
void offs_kernel(const int* __restrict__ hcnt, int* __restrict__ boff,
                 int* __restrict__ tot) {
    int k = blockIdx.x * 4 + (threadIdx.x >> 6);     // bucket
    int lane = threadIdx.x & 63;
    if (k >= MAXBUCK) return;
    int carry = 0;
    #pragma unroll
    for (int c = 0; c < NHB / 64; ++c) {
        int hb = c * 64 + lane;
        int v = hcnt[hb * MAXBUCK + k];
        int s = v;
        #pragma unroll
        for (int off = 1; off < 64; off <<= 1) {
            int u = __shfl_up(s, off, 64);
            if (lane >= off) s += u;
        }
        boff[hb * MAXBUCK + k] = carry + s - v;      // exclusive
        carry += __shfl(s, 63, 64);
    }
    if (lane == 0) tot[k] = carry;
}

// ---- bucket scan (1 block): exclusive scan of tot -> bbase -----------------

__global__ void bucket_scan_kernel(const int* __restrict__ tot,
                                   int* __restrict__ bbase, int nbuck) {
    __shared__ int part[256];
    int t = threadIdx.x;
    int lo = t * 4;
    int hi = min(lo + 4, nbuck);
    int loc[4];
    int s = 0;
    for (int i = lo; i < hi; ++i) { loc[i - lo] = tot[i]; s += loc[i - lo]; }
    part[t] = s;
    __syncthreads();
    for (int off = 1; off < 256; off <<= 1) {
        int v = (t >= off) ? part[t - off] : 0;
        __syncthreads();
        part[t] += v;
        __syncthreads();
    }
    int run = (t == 0) ? 0 : part[t - 1];
    for (int i = lo; i < hi; ++i) { bbase[i] = run; run += loc[i - lo]; }
    if (t == 255) bbase[nbuck] = part[255];
}

// ---- scatter edges into bucket-ordered 4B records (no global atomics) ------
// record = src | (dst&63)<<16

__global__ __launch_bounds__(256)
void scatter_kernel(const int* __restrict__ src, const int* __restrict__ dst,
                    const int* __restrict__ bbase, const int* __restrict__ boff,
                    uint32* __restrict__ recs, int E) {
    __shared__ int lh[MAXBUCK];
    __shared__ int lb[MAXBUCK];
    int t = threadIdx.x;
    int hb = blockIdx.x;
    int per = (E + NHB - 1) / NHB;
    int e0 = hb * per, e1 = min(e0 + per, E);
    for (int i = t; i < MAXBUCK; i += 256) {
        lh[i] = 0;
        lb[i] = bbase[i] + boff[hb * MAXBUCK + i];
    }
    __syncthreads();
    for (int e = e0 + t; e < e1; e += 256) {
        int d = dst[e];
        int b = d >> 6;
        int r = atomicAdd(&lh[b], 1);
        recs[lb[b] + r] = (uint32)src[e] | ((uint32)(d & 63) << 16);
    }
}

// ---- per-bucket counting sort: recs -> node-ordered esrc + rowptr ----------

__global__ __launch_bounds__(256)
void sort_kernel(const uint32* __restrict__ recs, const int* __restrict__ bbase,
                 int* __restrict__ rowptr, ushort16* __restrict__ esrc,
                 int N, int E) {
    __shared__ int lh[64];
    int b = blockIdx.x;
    int t = threadIdx.x;
    int s0 = bbase[b], s1 = bbase[b + 1];
    if (t < 64) lh[t] = 0;
    __syncthreads();
    for (int i = s0 + t; i < s1; i += 256)
        atomicAdd(&lh[recs[i] >> 16], 1);
    __syncthreads();
    if (t < 64) {
        int v = lh[t];
        int incl = v;
        #pragma unroll
        for (int off = 1; off < 64; off <<= 1) {
            int u = __shfl_up(incl, off, 64);
            if (t >= off) incl += u;
        }
        int excl = incl - v;
        int node = b * 64 + t;
        if (node < N) rowptr[node] = s0 + excl;
        lh[t] = excl;                    // becomes local cursor
    }
    __syncthreads();
    for (int i = s0 + t; i < s1; i += 256) {
        uint32 r = recs[i];
        int pos = atomicAdd(&lh[r >> 16], 1);
        esrc[s0 + pos] = (ushort16)(r & 0xFFFFu);
    }
    if (b == 0 && t == 0) rowptr[N] = E;
}

// ---- layer-1 aggregation (bf16 gather, register accum, 16-wide MLP) --------

__global__ void agg_mean_x_kernel(const uint32* __restrict__ xh,
                                  const int* __restrict__ rowptr,
                                  const ushort16* __restrict__ esrc,
                                  uint32* __restrict__ meanh, int N) {
    int node = blockIdx.x * 4 + (threadIdx.x >> 6);
    int lane = threadIdx.x & 63;
    if (node >= N) return;
    int s0 = rowptr[node], s1 = rowptr[node + 1];
    if (s0 == s1) { meanh[(size_t)node * 64 + lane] = 0u; return; }
    float ax[16] = {}, ay[16] = {};
    for (int k = s0; k < s1; k += 16) {
        int idx[16]; float msk[16];
        #pragma unroll
        for (int j = 0; j < 16; ++j) {
            int kj = k + j;
            idx[j] = esrc[kj < s1 ? kj : k];
            msk[j] = (kj < s1) ? 1.f : 0.f;
        }
        #pragma unroll
        for (int j = 0; j < 16; ++j) {
            uint32 v = xh[(size_t)idx[j] * 64 + lane];
            ax[j] += __uint_as_float(v << 16) * msk[j];
            ay[j] += __uint_as_float(v & 0xFFFF0000u) * msk[j];
        }
    }
    float sx = 0.f, sy = 0.f;
    #pragma unroll
    for (int j = 0; j < 16; ++j) { sx += ax[j]; sy += ay[j]; }
    float inv = 1.0f / (float)(s1 - s0);
    meanh[(size_t)node * 64 + lane] = (uint32)f2bf(sx * inv) | ((uint32)f2bf(sy * inv) << 16);
}

// ---- MFMA GEMM1 + fused GEMV epilogue --------------------------------------
// Per-wave 16 rows x 128 cols, 8 MFMA 16x16x32. h in registers only.
// A-frag: A[m=lane&15][k=quad*8+j]; D: row=quad*4+r, col=lane&15 (m89/m91).

__global__ __launch_bounds__(256)
void gemm1_mfma_kernel(const ushort16* __restrict__ meanh,
                       const ushort16* __restrict__ xh,
                       const ushort16* __restrict__ W1t,
                       const float* __restrict__ b1,
                       const float* __restrict__ fw,
                       float2* __restrict__ pab, float2* __restrict__ quv, int N) {
    int wave = threadIdx.x >> 6;
    int lane = threadIdx.x & 63;
    int m = lane & 15;
    int quad = lane >> 4;
    int row0 = blockIdx.x * 64 + wave * 16;
    int arow = row0 + m; if (arow > N - 1) arow = N - 1;
    f32x4 acc[8];
    #pragma unroll
    for (int c = 0; c < 8; ++c) acc[c] = (f32x4){0.f, 0.f, 0.f, 0.f};
    #pragma unroll
    for (int ks = 0; ks < 8; ++ks) {
        int k0 = ks * 32;
        const ushort16* Ab = (ks < 4) ? meanh : xh;
        bf16x8 a = *(const bf16x8*)(Ab + (size_t)arow * 128 + (k0 & 127) + quad * 8);
        #pragma unroll
        for (int c = 0; c < 8; ++c) {
            bf16x8 b = *(const bf16x8*)(W1t + (size_t)(c * 16 + m) * 256 + k0 + quad * 8);
            acc[c] = __builtin_amdgcn_mfma_f32_16x16x32_bf16(a, b, acc[c], 0, 0, 0);
        }
    }
    float da[4] = {}, dc[4] = {}, db[4] = {}, dd[4] = {};
    #pragma unroll
    for (int c = 0; c < 8; ++c) {
        int col = c * 16 + m;
        float bias = b1[col];
        float wa = fw[col], wc = fw[128 + col], wb = fw[256 + col], wd = fw[384 + col];
        #pragma unroll
        for (int r = 0; r < 4; ++r) {
            float v = fmaxf(acc[c][r] + bias, 0.f);
            da[r] += v * wa; dc[r] += v * wc; db[r] += v * wb; dd[r] += v * wd;
        }
    }
    #pragma unroll
    for (int r = 0; r < 4; ++r) {
        #pragma unroll
        for (int msk = 1; msk < 16; msk <<= 1) {
            da[r] += __shfl_xor(da[r], msk, 64);
            dc[r] += __shfl_xor(dc[r], msk, 64);
            db[r] += __shfl_xor(db[r], msk, 64);
            dd[r] += __shfl_xor(dd[r], msk, 64);
        }
    }
    if (m == 0) {
        #pragma unroll
        for (int r = 0; r < 4; ++r) {
            int grow = row0 + quad * 4 + r;
            if (grow < N) {
                pab[grow] = make_float2(da[r], dc[r]);
                quv[grow] = make_float2(db[r], dd[r]);
            }
        }
    }
}

// ---- layer-2 aggregation on folded scalars (thread/node, 8-wide MLP) -------

__global__ void agg_link_kernel(const float2* __restrict__ pab,
                                const float2* __restrict__ quv,
                                const int* __restrict__ rowptr,
                                const ushort16* __restrict__ esrc,
                                const float* __restrict__ fc,
                                float* __restrict__ za, float* __restrict__ zb, int N) {
    int i = blockIdx.x * blockDim.x + threadIdx.x;
    if (i >= N) return;
    int s0 = rowptr[i], s1 = rowptr[i + 1];
    float a[8] = {}, c[8] = {};
    for (int k = s0; k < s1; k += 8) {
        int idx[8]; float msk[8];
        #pragma unroll
        for (int j = 0; j < 8; ++j) {
            int kj = k + j;
            idx[j] = esrc[kj < s1 ? kj : k];
            msk[j] = (kj < s1) ? 1.f : 0.f;
        }
        #pragma unroll
        for (int j = 0; j < 8; ++j) {
            float2 p = pab[idx[j]];
            a[j] += p.x * msk[j];
            c[j] += p.y * msk[j];
        }
    }
    float spa = 0.f, spc = 0.f;
    #pragma unroll
    for (int j = 0; j < 8; ++j) { spa += a[j]; spc += c[j]; }
    float inv = (s1 > s0) ? 1.0f / (float)(s1 - s0) : 0.f;
    float2 q = quv[i];
    za[i] = spa * inv + q.x + fc[0];
    zb[i] = spc * inv + q.y + fc[1];
}

// ---- link prediction: out[p] = sigmoid(za[ps] + zb[pd] + blin) -------------

__global__ void link_kernel(const float* __restrict__ za, const float* __restrict__ zb,
                            const int* __restrict__ ps, const int* __restrict__ pd,
                            const float* __restrict__ blin,
                            float* __restrict__ out, int P) {
    int p = blockIdx.x * blockDim.x + threadIdx.x;
    if (p >= P) return;
    float logit = za[ps[p]] + zb[pd[p]] + blin[0];
    out[p] = 1.0f / (1.0f + expf(-logit));
}

// ---------------------------------------------------------------------------

extern "C" void kernel_launch(void* const* d_in, const int* in_sizes, int n_in,
                              void* d_out, int out_size, void* d_ws, size_t ws_size,
                              hipStream_t stream) {
    const float* x          = (const float*)d_in[0];
    const int*   edge_index = (const int*)d_in[1];
    const int*   edge_pairs = (const int*)d_in[2];
    const float* W1l        = (const float*)d_in[3];
    const float* b1         = (const float*)d_in[4];
    const float* W1r        = (const float*)d_in[5];
    const float* W2l        = (const float*)d_in[6];
    const float* b2         = (const float*)d_in[7];
    const float* W2r        = (const float*)d_in[8];
    const float* Wlin       = (const float*)d_in[9];
    const float* blin       = (const float*)d_in[10];
    float* out = (float*)d_out;

    const int N = in_sizes[0] / 128;       // 50000
    const int E = in_sizes[1] / 2;         // 800000
    const int P = in_sizes[2] / 2;         // 200000
    const int NBUCK = (N + 63) >> 6;       // 782

    const int* src = edge_index;
    const int* dst = edge_index + E;
    const int* ps  = edge_pairs;
    const int* pd  = edge_pairs + P;

    // workspace layout
    ushort16* xh    = (ushort16*)d_ws;                 // N*128 bf16
    ushort16* meanh = xh + (size_t)N * 128;            // N*128 bf16
    ushort16* W1t   = meanh + (size_t)N * 128;         // 128*256 bf16
    float* fw      = (float*)(W1t + 128 * 256);        // 512 f32
    float* fc      = fw + 512;                         // 2 f32 (+2 pad)
    float2* pab    = (float2*)(fc + 4);                // N float2
    float2* quv    = pab + N;                          // N float2
    float* za      = (float*)(quv + N);                // N f32
    float* zb      = za + N;                           // N f32
    int* bbase     = (int*)(zb + N);                   // NBUCK+1
    int* tot       = bbase + (MAXBUCK + 16);           // MAXBUCK
    int* hcnt      = tot + MAXBUCK;                    // NHB*MAXBUCK
    int* boff      = hcnt + NHB * MAXBUCK;             // NHB*MAXBUCK
    int* rowptr    = boff + NHB * MAXBUCK;             // N+1
    uint32* recs   = (uint32*)(rowptr + N + 16);       // E records
    ushort16* esrc = (ushort16*)(recs + E);            // E ushort

    const long long n4 = (long long)N * 128 / 4;       // 1.6M
    const int nbx  = (int)((n4 + 255) / 256);          // 6250
    const int nbw1 = 128;

    // fused prep: cast x, cast+transpose W1, fold W2/Wlin/b2, per-block hist
    prep_kernel<<<nbx + nbw1 + 1 + NHB, 256, 0, stream>>>(
        x, (uint32*)xh, n4, W1l, W1r, W1t, W2l, W2r, Wlin, b2, fw, fc,
        dst, hcnt, E, nbx, nbw1);

    // per-bucket block-offset scan, bucket base scan, scatter, sort
    offs_kernel<<<MAXBUCK / 4, 256, 0, stream>>>(hcnt, boff, tot);
    bucket_scan_kernel<<<1, 256, 0, stream>>>(tot, bbase, NBUCK);
    scatter_kernel<<<NHB, 256, 0, stream>>>(src, dst, bbase, boff, recs, E);
    sort_kernel<<<NBUCK, 256, 0, stream>>>(recs, bbase, rowptr, esrc, N, E);

    // layer 1: gather aggregation + MFMA GEMM with fused GEMV
    agg_mean_x_kernel<<<(N + 3) / 4, 256, 0, stream>>>((const uint32*)xh, rowptr, esrc,
                                                       (uint32*)meanh, N);
    gemm1_mfma_kernel<<<(N + 63) / 64, 256, 0, stream>>>(meanh, xh, W1t, b1, fw,
                                                         pab, quv, N);

    // folded layer 2: scalar gather aggregation
    agg_link_kernel<<<(N + 255) / 256, 256, 0, stream>>>(pab, quv, rowptr, esrc, fc,
                                                         za, zb, N);

    // link prediction
    link_kernel<<<(P + 255) / 256, 256, 0, stream>>>(za, zb, ps, pd, blin, out, P);
}